// Round 1
// baseline (492.072 us; speedup 1.0000x reference)
//
#include <hip/hip_runtime.h>

#define IN_DIM 128
#define HC     256      // H*C
#define CCH    64       // out channels per head
#define NH     4        // heads
#define NEG    0.2f

// ---------------- K0: per-relation attention term ----------------
// a_rel[r,h] = sum_c (rel_emb[r,:] . W_edge[h*64+c,:]) * att_edge[h,c]
__global__ void rel_attn_k(const float* __restrict__ rel_emb,
                           const float* __restrict__ W_edge,
                           const float* __restrict__ att_edge,
                           float* __restrict__ a_rel) {
  int r = blockIdx.x;
  int lane = threadIdx.x;  // 64 threads
  __shared__ float re[IN_DIM];
  re[lane]      = rel_emb[r * IN_DIM + lane];
  re[lane + 64] = rel_emb[r * IN_DIM + 64 + lane];
  __syncthreads();
  float p[NH];
#pragma unroll
  for (int h = 0; h < NH; ++h) {
    const float* wrow = W_edge + (size_t)(h * CCH + lane) * IN_DIM;
    float d = 0.f;
#pragma unroll
    for (int k = 0; k < IN_DIM; ++k) d += re[k] * wrow[k];
    p[h] = d * att_edge[h * CCH + lane];
  }
#pragma unroll
  for (int off = 32; off; off >>= 1) {
#pragma unroll
    for (int h = 0; h < NH; ++h) p[h] += __shfl_down(p[h], off);
  }
  if (lane == 0) {
#pragma unroll
    for (int h = 0; h < NH; ++h) a_rel[r * NH + h] = p[h];
  }
}

// ---------------- K1: x_proj = x @ W.T  (M=N nodes, N=256, K=128) ----------------
// 64x64 tile, 256 threads, 4x4 per thread
__global__ void gemm_xw_k(const float* __restrict__ x,
                          const float* __restrict__ W,
                          float* __restrict__ xp, int Nn) {
  __shared__ float As[16][65];  // [k][m]
  __shared__ float Bs[16][65];  // [k][n]
  int bm = blockIdx.x * 64;
  int bn = blockIdx.y * 64;
  int tid = threadIdx.x;
  int tr = tid >> 4, tc = tid & 15;
  float acc[4][4] = {};
  for (int k0 = 0; k0 < IN_DIM; k0 += 16) {
    for (int i = tid; i < 64 * 16; i += 256) {
      int m = i >> 4, kk = i & 15;
      int gm = bm + m;
      As[kk][m] = (gm < Nn) ? x[(size_t)gm * IN_DIM + k0 + kk] : 0.f;
    }
    for (int i = tid; i < 64 * 16; i += 256) {
      int n = i >> 4, kk = i & 15;
      Bs[kk][n] = W[(size_t)(bn + n) * IN_DIM + k0 + kk];
    }
    __syncthreads();
#pragma unroll
    for (int kk = 0; kk < 16; ++kk) {
      float a[4], b[4];
#pragma unroll
      for (int i = 0; i < 4; ++i) a[i] = As[kk][tr * 4 + i];
#pragma unroll
      for (int j = 0; j < 4; ++j) b[j] = Bs[kk][tc * 4 + j];
#pragma unroll
      for (int i = 0; i < 4; ++i)
#pragma unroll
        for (int j = 0; j < 4; ++j) acc[i][j] += a[i] * b[j];
    }
    __syncthreads();
  }
#pragma unroll
  for (int i = 0; i < 4; ++i) {
    int gm = bm + tr * 4 + i;
    if (gm < Nn) {
#pragma unroll
      for (int j = 0; j < 4; ++j)
        xp[(size_t)gm * HC + bn + tc * 4 + j] = acc[i][j];
    }
  }
}

// ---------------- K2: a_src / a_dst per node ----------------
__global__ void attn_nodes_k(const float* __restrict__ xp,
                             const float* __restrict__ att_src,
                             const float* __restrict__ att_dst,
                             float* __restrict__ a_src,
                             float* __restrict__ a_dst, int Nn) {
  int node = blockIdx.x * 4 + (threadIdx.x >> 6);
  int lane = threadIdx.x & 63;
  if (node >= Nn) return;
  float ps[NH], pd[NH];
#pragma unroll
  for (int h = 0; h < NH; ++h) {
    float v = xp[(size_t)node * HC + h * CCH + lane];
    ps[h] = v * att_src[h * CCH + lane];
    pd[h] = v * att_dst[h * CCH + lane];
  }
#pragma unroll
  for (int off = 32; off; off >>= 1) {
#pragma unroll
    for (int h = 0; h < NH; ++h) {
      ps[h] += __shfl_down(ps[h], off);
      pd[h] += __shfl_down(pd[h], off);
    }
  }
  if (lane == 0) {
#pragma unroll
    for (int h = 0; h < NH; ++h) {
      a_src[node * NH + h] = ps[h];
      a_dst[node * NH + h] = pd[h];
    }
  }
}

// ---------------- K3: init out = bias ----------------
__global__ void init_out_k(float* __restrict__ out,
                           const float* __restrict__ bias, int total) {
  int i = blockIdx.x * 256 + threadIdx.x;
  if (i < total) out[i] = bias[i & (CCH - 1)];
}

// ---------------- K4: edge pass 1 — w = exp(lrelu(alpha)), z[dst,h] += w ----------------
__global__ void edge_z_k(const int* __restrict__ src, const int* __restrict__ dst,
                         const int* __restrict__ etype,
                         const float* __restrict__ a_src, const float* __restrict__ a_dst,
                         const float* __restrict__ a_rel,
                         float* __restrict__ w_e, float* __restrict__ z, int E) {
  int e = blockIdx.x * 256 + threadIdx.x;
  if (e >= E) return;
  int s = src[e], d = dst[e], t = etype[e];
  const float4 as = *(const float4*)(a_src + (size_t)s * NH);
  const float4 ad = *(const float4*)(a_dst + (size_t)d * NH);
  const float4 ar = *(const float4*)(a_rel + (size_t)t * NH);
  float al, w[NH];
  al = as.x + ad.x + ar.x; al = al > 0.f ? al : NEG * al; w[0] = __expf(al);
  al = as.y + ad.y + ar.y; al = al > 0.f ? al : NEG * al; w[1] = __expf(al);
  al = as.z + ad.z + ar.z; al = al > 0.f ? al : NEG * al; w[2] = __expf(al);
  al = as.w + ad.w + ar.w; al = al > 0.f ? al : NEG * al; w[3] = __expf(al);
  *(float4*)(w_e + (size_t)e * NH) = make_float4(w[0], w[1], w[2], w[3]);
#pragma unroll
  for (int h = 0; h < NH; ++h) atomicAdd(&z[(size_t)d * NH + h], w[h]);
}

// ---------------- K5: edge pass 2 — out[dst] += (1/H) sum_h alpha_h * xp[src,h,:] ----------------
__global__ void edge_msg_k(const int* __restrict__ src, const int* __restrict__ dst,
                           const float* __restrict__ xp, const float* __restrict__ w_e,
                           const float* __restrict__ z, float* __restrict__ out, int E) {
  int e = blockIdx.x * 4 + (threadIdx.x >> 6);
  int lane = threadIdx.x & 63;
  if (e >= E) return;
  int s = src[e], d = dst[e];
  const float4 w  = *(const float4*)(w_e + (size_t)e * NH);
  const float4 zz = *(const float4*)(z + (size_t)d * NH);
  float a0 = 0.25f * w.x / (zz.x + 1e-16f);
  float a1 = 0.25f * w.y / (zz.y + 1e-16f);
  float a2 = 0.25f * w.z / (zz.z + 1e-16f);
  float a3 = 0.25f * w.w / (zz.w + 1e-16f);
  const float* xr = xp + (size_t)s * HC;
  float t = a0 * xr[lane] + a1 * xr[64 + lane] + a2 * xr[128 + lane] + a3 * xr[192 + lane];
  atomicAdd(&out[(size_t)d * CCH + lane], t);
}

extern "C" void kernel_launch(void* const* d_in, const int* in_sizes, int n_in,
                              void* d_out, int out_size, void* d_ws, size_t ws_size,
                              hipStream_t stream) {
  const float* x        = (const float*)d_in[0];
  const int*   eidx     = (const int*)d_in[1];
  const int*   etype    = (const int*)d_in[2];
  const float* rel_emb  = (const float*)d_in[3];
  const float* W        = (const float*)d_in[4];
  const float* att_src  = (const float*)d_in[5];
  const float* att_dst  = (const float*)d_in[6];
  const float* W_edge   = (const float*)d_in[7];
  const float* att_edge = (const float*)d_in[8];
  const float* bias     = (const float*)d_in[9];
  float* out = (float*)d_out;

  const int Nn = in_sizes[0] / IN_DIM;
  const int E  = in_sizes[1] / 2;
  const int R  = in_sizes[3] / IN_DIM;
  const int* src = eidx;
  const int* dst = eidx + E;

  // workspace layout (bytes)
  char* ws = (char*)d_ws;
  float* xp    = (float*)(ws);                               // Nn*256 f32
  float* a_src = (float*)(ws + (size_t)Nn * HC * 4);         // Nn*4
  float* a_dst = a_src + (size_t)Nn * NH;                    // Nn*4
  float* a_rel = a_dst + (size_t)Nn * NH;                    // R*4
  float* w_e   = a_rel + (size_t)R * NH;                     // E*4
  float* z     = w_e + (size_t)E * NH;                       // Nn*4

  // K0: relation attention
  hipLaunchKernelGGL(rel_attn_k, dim3(R), dim3(64), 0, stream,
                     rel_emb, W_edge, att_edge, a_rel);
  // K1: x_proj GEMM
  dim3 gg((Nn + 63) / 64, HC / 64);
  hipLaunchKernelGGL(gemm_xw_k, gg, dim3(256), 0, stream, x, W, xp, Nn);
  // K2: node attention terms
  hipLaunchKernelGGL(attn_nodes_k, dim3((Nn + 3) / 4), dim3(256), 0, stream,
                     xp, att_src, att_dst, a_src, a_dst, Nn);
  // K3: init out = bias
  hipLaunchKernelGGL(init_out_k, dim3((Nn * CCH + 255) / 256), dim3(256), 0, stream,
                     out, bias, Nn * CCH);
  // zero z accumulator
  hipMemsetAsync(z, 0, (size_t)Nn * NH * sizeof(float), stream);
  // K4: edge softmax denominator
  hipLaunchKernelGGL(edge_z_k, dim3((E + 255) / 256), dim3(256), 0, stream,
                     src, dst, etype, a_src, a_dst, a_rel, w_e, z, E);
  // K5: edge messages
  hipLaunchKernelGGL(edge_msg_k, dim3((E + 3) / 4), dim3(256), 0, stream,
                     src, dst, xp, w_e, z, out, E);
}

// Round 2
// 374.704 us; speedup vs baseline: 1.3132x; 1.3132x over previous
//
#include <hip/hip_runtime.h>

#define IN_DIM 128
#define HC     256      // H*C
#define CCH    64
#define NH     4
#define NEG    0.2f

static __device__ __forceinline__ unsigned short f2bf(float f) {
  unsigned int u = __float_as_uint(f);
  u = (u + 0x7fffu + ((u >> 16) & 1u)) >> 16;   // RNE
  return (unsigned short)u;
}
static __device__ __forceinline__ float bf2f(unsigned short b) {
  return __uint_as_float(((unsigned int)b) << 16);
}

// ---------------- K0: per-relation attention term ----------------
__global__ void rel_attn_k(const float* __restrict__ rel_emb,
                           const float* __restrict__ W_edge,
                           const float* __restrict__ att_edge,
                           float* __restrict__ a_rel) {
  int r = blockIdx.x;
  int lane = threadIdx.x;  // 64 threads
  __shared__ float re[IN_DIM];
  re[lane]      = rel_emb[r * IN_DIM + lane];
  re[lane + 64] = rel_emb[r * IN_DIM + 64 + lane];
  __syncthreads();
  float p[NH];
#pragma unroll
  for (int h = 0; h < NH; ++h) {
    const float* wrow = W_edge + (size_t)(h * CCH + lane) * IN_DIM;
    float d = 0.f;
#pragma unroll
    for (int k = 0; k < IN_DIM; ++k) d += re[k] * wrow[k];
    p[h] = d * att_edge[h * CCH + lane];
  }
#pragma unroll
  for (int off = 32; off; off >>= 1) {
#pragma unroll
    for (int h = 0; h < NH; ++h) p[h] += __shfl_down(p[h], off);
  }
  if (lane == 0) {
#pragma unroll
    for (int h = 0; h < NH; ++h) a_rel[r * NH + h] = p[h];
  }
}

// ---------------- K1: fused GEMM: xp(bf16) + a_src/a_dst (f32) ----------------
// 64x64 tile; block column bn covers exactly one head (bn/64).
__global__ void gemm_fused_k(const float* __restrict__ x, const float* __restrict__ W,
                             const float* __restrict__ att_src, const float* __restrict__ att_dst,
                             unsigned short* __restrict__ xpb,
                             float* __restrict__ a_srcv, float* __restrict__ a_dstv, int Nn) {
  __shared__ float As[16][65];
  __shared__ float Bs[16][65];
  int bm = blockIdx.x * 64, bn = blockIdx.y * 64;
  int tid = threadIdx.x, tr = tid >> 4, tc = tid & 15;
  float acc[4][4] = {};
  for (int k0 = 0; k0 < IN_DIM; k0 += 16) {
    for (int i = tid; i < 1024; i += 256) {
      int m = i >> 4, kk = i & 15;
      int gm = bm + m;
      As[kk][m] = (gm < Nn) ? x[(size_t)gm * IN_DIM + k0 + kk] : 0.f;
    }
    for (int i = tid; i < 1024; i += 256) {
      int nn = i >> 4, kk = i & 15;
      Bs[kk][nn] = W[(size_t)(bn + nn) * IN_DIM + k0 + kk];
    }
    __syncthreads();
#pragma unroll
    for (int kk = 0; kk < 16; ++kk) {
      float a[4], b[4];
#pragma unroll
      for (int i = 0; i < 4; ++i) a[i] = As[kk][tr * 4 + i];
#pragma unroll
      for (int j = 0; j < 4; ++j) b[j] = Bs[kk][tc * 4 + j];
#pragma unroll
      for (int i = 0; i < 4; ++i)
#pragma unroll
        for (int j = 0; j < 4; ++j) acc[i][j] += a[i] * b[j];
    }
    __syncthreads();
  }
  int h = bn >> 6;
  float s4[4], d4[4];
#pragma unroll
  for (int j = 0; j < 4; ++j) {
    s4[j] = att_src[h * CCH + tc * 4 + j];
    d4[j] = att_dst[h * CCH + tc * 4 + j];
  }
#pragma unroll
  for (int i = 0; i < 4; ++i) {
    int gm = bm + tr * 4 + i;
    if (gm < Nn) {
      ushort4 u;
      u.x = f2bf(acc[i][0]); u.y = f2bf(acc[i][1]);
      u.z = f2bf(acc[i][2]); u.w = f2bf(acc[i][3]);
      *(ushort4*)(xpb + (size_t)gm * HC + bn + tc * 4) = u;
    }
    float ps = 0.f, pd = 0.f;
#pragma unroll
    for (int j = 0; j < 4; ++j) { ps += acc[i][j] * s4[j]; pd += acc[i][j] * d4[j]; }
#pragma unroll
    for (int off = 8; off; off >>= 1) {
      ps += __shfl_down(ps, off);
      pd += __shfl_down(pd, off);
    }
    if (tc == 0 && gm < Nn) {
      a_srcv[(size_t)gm * NH + h] = ps;
      a_dstv[(size_t)gm * NH + h] = pd;
    }
  }
}

// ---------------- K2: histogram of dst ----------------
__global__ void hist_k(const int* __restrict__ dst, int* __restrict__ counts, int E) {
  int e = blockIdx.x * 256 + threadIdx.x;
  if (e < E) atomicAdd(&counts[dst[e]], 1);
}

// ---------------- K3: single-block exclusive scan -> offsets + cursor ----------------
__global__ void scan_k(const int* __restrict__ counts, int* __restrict__ offsets,
                       int* __restrict__ cursor, int n) {
  __shared__ int sums[1024];
  __shared__ int carry;
  int tid = threadIdx.x;
  if (tid == 0) carry = 0;
  __syncthreads();
  for (int base = 0; base < n; base += 8192) {
    int v[8]; int s = 0;
    int i0 = base + tid * 8;
#pragma unroll
    for (int k = 0; k < 8; ++k) { int i = i0 + k; int c = (i < n) ? counts[i] : 0; v[k] = s; s += c; }
    sums[tid] = s;
    __syncthreads();
    int chunkbase = carry;
    for (int off = 1; off < 1024; off <<= 1) {
      int t = (tid >= off) ? sums[tid - off] : 0;
      __syncthreads();
      sums[tid] += t;
      __syncthreads();
    }
    int excl = chunkbase + (tid ? sums[tid - 1] : 0);
#pragma unroll
    for (int k = 0; k < 8; ++k) {
      int i = i0 + k;
      if (i < n) { int o = excl + v[k]; offsets[i] = o; cursor[i] = o; }
    }
    if (tid == 1023) carry = chunkbase + sums[1023];
    __syncthreads();
  }
  if (tid == 0) offsets[n] = carry;
}

// ---------------- K4: scatter edges into dst-sorted order ----------------
__global__ void scatter_k(const int* __restrict__ src, const int* __restrict__ dst,
                          const int* __restrict__ et, int* __restrict__ cursor,
                          int* __restrict__ ssrc, int* __restrict__ sety, int E) {
  int e = blockIdx.x * 256 + threadIdx.x;
  if (e >= E) return;
  int d = dst[e];
  int pos = atomicAdd(&cursor[d], 1);
  ssrc[pos] = src[e];
  sety[pos] = et[e];
}

// ---------------- K5: one wave per dst: softmax + message accumulate + write ----------------
__global__ void gat_out_k(const int* __restrict__ offsets,
                          const int* __restrict__ ssrc, const int* __restrict__ sety,
                          const float* __restrict__ a_srcv, const float* __restrict__ a_dstv,
                          const float* __restrict__ a_rel,
                          const unsigned short* __restrict__ xpb,
                          const float* __restrict__ bias,
                          float* __restrict__ out, int Nn) {
  int d = blockIdx.x * 4 + (threadIdx.x >> 6);
  if (d >= Nn) return;
  int lane = threadIdx.x & 63;
  int h = lane >> 4, c4 = (lane & 15) * 4;
  int beg = offsets[d], end = offsets[d + 1];
  float ad = a_dstv[(size_t)d * NH + h];
  float z = 0.f, acc0 = 0.f, acc1 = 0.f, acc2 = 0.f, acc3 = 0.f;
  for (int j = beg; j < end; ++j) {
    int s = ssrc[j], t = sety[j];
    float al = a_srcv[(size_t)s * NH + h] + ad + a_rel[t * NH + h];
    al = al > 0.f ? al : NEG * al;
    float w = __expf(al);
    z += w;
    ushort4 u = *(const ushort4*)(xpb + (size_t)s * HC + h * CCH + c4);
    acc0 += w * bf2f(u.x);
    acc1 += w * bf2f(u.y);
    acc2 += w * bf2f(u.z);
    acc3 += w * bf2f(u.w);
  }
  float inv = 0.25f / (z + 1e-16f);
  acc0 *= inv; acc1 *= inv; acc2 *= inv; acc3 *= inv;
  acc0 += __shfl_down(acc0, 32); acc1 += __shfl_down(acc1, 32);
  acc2 += __shfl_down(acc2, 32); acc3 += __shfl_down(acc3, 32);
  acc0 += __shfl_down(acc0, 16); acc1 += __shfl_down(acc1, 16);
  acc2 += __shfl_down(acc2, 16); acc3 += __shfl_down(acc3, 16);
  if (lane < 16) {
    const float4 b4 = *(const float4*)(bias + lane * 4);
    float4 o;
    o.x = acc0 + b4.x; o.y = acc1 + b4.y; o.z = acc2 + b4.z; o.w = acc3 + b4.w;
    *(float4*)(out + (size_t)d * CCH + lane * 4) = o;
  }
}

extern "C" void kernel_launch(void* const* d_in, const int* in_sizes, int n_in,
                              void* d_out, int out_size, void* d_ws, size_t ws_size,
                              hipStream_t stream) {
  const float* x        = (const float*)d_in[0];
  const int*   eidx     = (const int*)d_in[1];
  const int*   etype    = (const int*)d_in[2];
  const float* rel_emb  = (const float*)d_in[3];
  const float* W        = (const float*)d_in[4];
  const float* att_src  = (const float*)d_in[5];
  const float* att_dst  = (const float*)d_in[6];
  const float* W_edge   = (const float*)d_in[7];
  const float* att_edge = (const float*)d_in[8];
  const float* bias     = (const float*)d_in[9];
  float* out = (float*)d_out;

  const int Nn = in_sizes[0] / IN_DIM;
  const int E  = in_sizes[1] / 2;
  const int R  = in_sizes[3] / IN_DIM;
  const int* src = eidx;
  const int* dst = eidx + E;

  // workspace layout (256B-aligned chunks)
  char* ws = (char*)d_ws;
  size_t off = 0;
  auto alloc = [&](size_t bytes) {
    void* p = ws + off;
    off = (off + bytes + 255) & ~(size_t)255;
    return p;
  };
  unsigned short* xpb = (unsigned short*)alloc((size_t)Nn * HC * 2);
  float* a_srcv = (float*)alloc((size_t)Nn * NH * 4);
  float* a_dstv = (float*)alloc((size_t)Nn * NH * 4);
  float* a_rel  = (float*)alloc((size_t)R * NH * 4);
  int*   counts = (int*)alloc((size_t)Nn * 4);
  int*   offsets= (int*)alloc((size_t)(Nn + 1) * 4);
  int*   cursor = (int*)alloc((size_t)Nn * 4);
  int*   ssrc   = (int*)alloc((size_t)E * 4);
  int*   sety   = (int*)alloc((size_t)E * 4);

  // K0: relation attention
  hipLaunchKernelGGL(rel_attn_k, dim3(R), dim3(64), 0, stream,
                     rel_emb, W_edge, att_edge, a_rel);
  // K1: fused GEMM + node attention
  dim3 gg((Nn + 63) / 64, HC / 64);
  hipLaunchKernelGGL(gemm_fused_k, gg, dim3(256), 0, stream,
                     x, W, att_src, att_dst, xpb, a_srcv, a_dstv, Nn);
  // CSR build
  hipMemsetAsync(counts, 0, (size_t)Nn * 4, stream);
  hipLaunchKernelGGL(hist_k, dim3((E + 255) / 256), dim3(256), 0, stream, dst, counts, E);
  hipLaunchKernelGGL(scan_k, dim3(1), dim3(1024), 0, stream, counts, offsets, cursor, Nn);
  hipLaunchKernelGGL(scatter_k, dim3((E + 255) / 256), dim3(256), 0, stream,
                     src, dst, etype, cursor, ssrc, sety, E);
  // K5: fused softmax + aggregate
  hipLaunchKernelGGL(gat_out_k, dim3((Nn + 3) / 4), dim3(256), 0, stream,
                     offsets, ssrc, sety, a_srcv, a_dstv, a_rel, xpb, bias, out, Nn);
}

// Round 3
// 223.794 us; speedup vs baseline: 2.1988x; 1.6743x over previous
//
#include <hip/hip_runtime.h>

#define IN_DIM 128
#define HC     256      // H*C
#define CCH    64
#define NH     4
#define NEG    0.2f

typedef __attribute__((ext_vector_type(4))) float f32x4;
typedef __attribute__((ext_vector_type(8))) short short8;

static __device__ __forceinline__ unsigned short f2bf(float f) {
  unsigned int u = __float_as_uint(f);
  u = (u + 0x7fffu + ((u >> 16) & 1u)) >> 16;   // RNE
  return (unsigned short)u;
}
static __device__ __forceinline__ float bf2f(unsigned short b) {
  return __uint_as_float(((unsigned int)b) << 16);
}

// ---------------- K0: per-relation attention term ----------------
__global__ void rel_attn_k(const float* __restrict__ rel_emb,
                           const float* __restrict__ W_edge,
                           const float* __restrict__ att_edge,
                           float* __restrict__ a_rel) {
  int r = blockIdx.x;
  int lane = threadIdx.x;  // 64 threads
  __shared__ float re[IN_DIM];
  re[lane]      = rel_emb[r * IN_DIM + lane];
  re[lane + 64] = rel_emb[r * IN_DIM + 64 + lane];
  __syncthreads();
  float p[NH];
#pragma unroll
  for (int h = 0; h < NH; ++h) {
    const float* wrow = W_edge + (size_t)(h * CCH + lane) * IN_DIM;
    float d = 0.f;
#pragma unroll
    for (int k = 0; k < IN_DIM; ++k) d += re[k] * wrow[k];
    p[h] = d * att_edge[h * CCH + lane];
  }
#pragma unroll
  for (int off = 32; off; off >>= 1) {
#pragma unroll
    for (int h = 0; h < NH; ++h) p[h] += __shfl_down(p[h], off);
  }
  if (lane == 0) {
#pragma unroll
    for (int h = 0; h < NH; ++h) a_rel[r * NH + h] = p[h];
  }
}

// ---------------- K1: MFMA bf16 GEMM (M=Nn, N=256, K=128) + fused a_src/a_dst ----------------
// BM=128, BN=64 (one head per block). grid = (4, ceil(Nn/128)) — head fastest for L2 reuse of x.
__global__ __launch_bounds__(256) void gemm_mfma_k(
    const float* __restrict__ x, const float* __restrict__ W,
    const float* __restrict__ att_src, const float* __restrict__ att_dst,
    unsigned short* __restrict__ xpb, float* __restrict__ a_srcv,
    float* __restrict__ a_dstv, int Nn) {
  __shared__ unsigned short Asm[128][136];  // +8 pad: row stride 272B -> 2-way max
  __shared__ unsigned short Bsm[64][136];
  const int tid = threadIdx.x;
  const int h  = blockIdx.x;
  const int bm = blockIdx.y * 128;
  const int bn = h * CCH;

  // stage A (x rows bm..bm+127, f32 -> bf16)
  {
    int row = tid >> 1, ch = (tid & 1) * 64;
    int gm = bm + row;
    if (gm < Nn) {
      const float* xr = x + (size_t)gm * IN_DIM + ch;
#pragma unroll
      for (int i = 0; i < 64; i += 8) {
        float4 a = *(const float4*)(xr + i);
        float4 b = *(const float4*)(xr + i + 4);
        ushort4 u0, u1;
        u0.x = f2bf(a.x); u0.y = f2bf(a.y); u0.z = f2bf(a.z); u0.w = f2bf(a.w);
        u1.x = f2bf(b.x); u1.y = f2bf(b.y); u1.z = f2bf(b.z); u1.w = f2bf(b.w);
        *(ushort4*)&Asm[row][ch + i]     = u0;
        *(ushort4*)&Asm[row][ch + i + 4] = u1;
      }
    } else {
      ushort4 zz = {0, 0, 0, 0};
#pragma unroll
      for (int i = 0; i < 64; i += 4) *(ushort4*)&Asm[row][ch + i] = zz;
    }
  }
  // stage B (W rows bn..bn+63)
  if (tid < 128) {
    int row = tid >> 1, ch = (tid & 1) * 64;
    const float* wr = W + (size_t)(bn + row) * IN_DIM + ch;
#pragma unroll
    for (int i = 0; i < 64; i += 8) {
      float4 a = *(const float4*)(wr + i);
      float4 b = *(const float4*)(wr + i + 4);
      ushort4 u0, u1;
      u0.x = f2bf(a.x); u0.y = f2bf(a.y); u0.z = f2bf(a.z); u0.w = f2bf(a.w);
      u1.x = f2bf(b.x); u1.y = f2bf(b.y); u1.z = f2bf(b.z); u1.w = f2bf(b.w);
      *(ushort4*)&Bsm[row][ch + i]     = u0;
      *(ushort4*)&Bsm[row][ch + i + 4] = u1;
    }
  }
  __syncthreads();

  const int wv = tid >> 6, lane = tid & 63;
  const int lr = lane & 15, lk = lane >> 4;
  f32x4 acc[2][4] = {};
#pragma unroll
  for (int kk = 0; kk < 4; ++kk) {
    const int ko = kk * 32 + lk * 8;
    short8 af0 = *(const short8*)&Asm[wv * 32 + lr][ko];
    short8 af1 = *(const short8*)&Asm[wv * 32 + 16 + lr][ko];
    short8 bf0 = *(const short8*)&Bsm[lr][ko];
    short8 bf1 = *(const short8*)&Bsm[16 + lr][ko];
    short8 bf2v = *(const short8*)&Bsm[32 + lr][ko];
    short8 bf3 = *(const short8*)&Bsm[48 + lr][ko];
    acc[0][0] = __builtin_amdgcn_mfma_f32_16x16x32_bf16(af0, bf0, acc[0][0], 0, 0, 0);
    acc[0][1] = __builtin_amdgcn_mfma_f32_16x16x32_bf16(af0, bf1, acc[0][1], 0, 0, 0);
    acc[0][2] = __builtin_amdgcn_mfma_f32_16x16x32_bf16(af0, bf2v, acc[0][2], 0, 0, 0);
    acc[0][3] = __builtin_amdgcn_mfma_f32_16x16x32_bf16(af0, bf3, acc[0][3], 0, 0, 0);
    acc[1][0] = __builtin_amdgcn_mfma_f32_16x16x32_bf16(af1, bf0, acc[1][0], 0, 0, 0);
    acc[1][1] = __builtin_amdgcn_mfma_f32_16x16x32_bf16(af1, bf1, acc[1][1], 0, 0, 0);
    acc[1][2] = __builtin_amdgcn_mfma_f32_16x16x32_bf16(af1, bf2v, acc[1][2], 0, 0, 0);
    acc[1][3] = __builtin_amdgcn_mfma_f32_16x16x32_bf16(af1, bf3, acc[1][3], 0, 0, 0);
  }

  // epilogue: xpb (bf16) + a_src/a_dst (f32)
  float as4[4], ad4[4];
#pragma unroll
  for (int ni = 0; ni < 4; ++ni) {
    as4[ni] = att_src[h * CCH + ni * 16 + lr];
    ad4[ni] = att_dst[h * CCH + ni * 16 + lr];
  }
#pragma unroll
  for (int mi = 0; mi < 2; ++mi) {
#pragma unroll
    for (int r = 0; r < 4; ++r) {
      int gm = bm + wv * 32 + mi * 16 + lk * 4 + r;
      bool ok = (gm < Nn);
      if (ok) {
#pragma unroll
        for (int ni = 0; ni < 4; ++ni)
          xpb[(size_t)gm * HC + bn + ni * 16 + lr] = f2bf(acc[mi][ni][r]);
      }
      float ps = 0.f, pd = 0.f;
#pragma unroll
      for (int ni = 0; ni < 4; ++ni) {
        ps += acc[mi][ni][r] * as4[ni];
        pd += acc[mi][ni][r] * ad4[ni];
      }
      ps += __shfl_xor(ps, 1); pd += __shfl_xor(pd, 1);
      ps += __shfl_xor(ps, 2); pd += __shfl_xor(pd, 2);
      ps += __shfl_xor(ps, 4); pd += __shfl_xor(pd, 4);
      ps += __shfl_xor(ps, 8); pd += __shfl_xor(pd, 8);
      if (lr == 0 && ok) {
        a_srcv[(size_t)gm * NH + h] = ps;
        a_dstv[(size_t)gm * NH + h] = pd;
      }
    }
  }
}

// ---------------- K2: histogram of dst ----------------
__global__ void hist_k(const int* __restrict__ dst, int* __restrict__ counts, int E) {
  int e = blockIdx.x * 256 + threadIdx.x;
  if (e < E) atomicAdd(&counts[dst[e]], 1);
}

// ---------------- scan phase A: per-block (4096) reduce ----------------
__global__ void scanA_k(const int* __restrict__ counts, int* __restrict__ bsum, int n) {
  __shared__ int ts[256];
  int b = blockIdx.x, tid = threadIdx.x;
  int i0 = b * 4096 + tid * 16;
  int s = 0;
#pragma unroll
  for (int k = 0; k < 16; ++k) {
    int i = i0 + k;
    s += (i < n) ? counts[i] : 0;
  }
  ts[tid] = s;
  __syncthreads();
  for (int off = 128; off; off >>= 1) {
    if (tid < off) ts[tid] += ts[tid + off];
    __syncthreads();
  }
  if (tid == 0) bsum[b] = ts[0];
}

// ---------------- scan phase B: 1 wave scans <=64 block sums ----------------
__global__ void scanB_k(const int* __restrict__ bsum, int* __restrict__ bbase,
                        int nb, int* __restrict__ offsets, int n, int E) {
  int lane = threadIdx.x;
  int v = (lane < nb) ? bsum[lane] : 0;
  int orig = v;
#pragma unroll
  for (int off = 1; off < 64; off <<= 1) {
    int t = __shfl_up(v, off);
    if (lane >= off) v += t;
  }
  if (lane < nb) bbase[lane] = v - orig;
  if (lane == 0) offsets[n] = E;
}

// ---------------- scan phase C: rescan + write offsets & cursor ----------------
__global__ void scanC_k(const int* __restrict__ counts, const int* __restrict__ bbase,
                        int* __restrict__ offsets, int* __restrict__ cursor, int n) {
  __shared__ int ts[256];
  int b = blockIdx.x, tid = threadIdx.x;
  int i0 = b * 4096 + tid * 16;
  int pre[16];
  int s = 0;
#pragma unroll
  for (int k = 0; k < 16; ++k) {
    int i = i0 + k;
    pre[k] = s;
    s += (i < n) ? counts[i] : 0;
  }
  ts[tid] = s;
  __syncthreads();
  for (int off = 1; off < 256; off <<= 1) {
    int t = (tid >= off) ? ts[tid - off] : 0;
    __syncthreads();
    ts[tid] += t;
    __syncthreads();
  }
  int base = bbase[b] + (tid ? ts[tid - 1] : 0);
#pragma unroll
  for (int k = 0; k < 16; ++k) {
    int i = i0 + k;
    if (i < n) {
      int o = base + pre[k];
      offsets[i] = o;
      cursor[i] = o;
    }
  }
}

// ---------------- K4: per-edge weights + scatter into dst-sorted order ----------------
__global__ void edge_w_k(const int* __restrict__ src, const int* __restrict__ dst,
                         const int* __restrict__ et,
                         const float* __restrict__ a_srcv, const float* __restrict__ a_dstv,
                         const float* __restrict__ a_rel, int R,
                         int* __restrict__ cursor,
                         int* __restrict__ ssrc2, float* __restrict__ wq, int E) {
  __shared__ float4 arl[64];
  int tid = threadIdx.x;
  if (tid < R && tid < 64) arl[tid] = ((const float4*)a_rel)[tid];
  __syncthreads();
  int e = blockIdx.x * 256 + tid;
  if (e >= E) return;
  int s = src[e], d = dst[e], t = et[e];
  float4 as = *(const float4*)(a_srcv + (size_t)s * NH);
  float4 ad = *(const float4*)(a_dstv + (size_t)d * NH);
  float4 ar = arl[t];
  float al;
  float4 w;
  al = as.x + ad.x + ar.x; al = al > 0.f ? al : NEG * al; w.x = __expf(al);
  al = as.y + ad.y + ar.y; al = al > 0.f ? al : NEG * al; w.y = __expf(al);
  al = as.z + ad.z + ar.z; al = al > 0.f ? al : NEG * al; w.z = __expf(al);
  al = as.w + ad.w + ar.w; al = al > 0.f ? al : NEG * al; w.w = __expf(al);
  int pos = atomicAdd(&cursor[d], 1);
  ssrc2[pos] = s;
  *(float4*)(wq + (size_t)pos * NH) = w;
}

// ---------------- K5: one wave per dst: z + messages + write ----------------
__global__ void gat_out_k(const int* __restrict__ offsets,
                          const int* __restrict__ ssrc2, const float* __restrict__ wqf,
                          const unsigned short* __restrict__ xpb,
                          const float* __restrict__ bias,
                          float* __restrict__ out, int Nn) {
  int d = blockIdx.x * 4 + (threadIdx.x >> 6);
  if (d >= Nn) return;
  int lane = threadIdx.x & 63;
  int h = lane >> 4, c4 = (lane & 15) * 4;
  int beg = offsets[d], end = offsets[d + 1];
  float z = 0.f, a0 = 0.f, a1 = 0.f, a2 = 0.f, a3 = 0.f;
  int j = beg;
  for (; j + 2 <= end; j += 2) {
    int s0 = ssrc2[j], s1 = ssrc2[j + 1];
    float w0 = wqf[(size_t)j * NH + h];
    float w1 = wqf[(size_t)(j + 1) * NH + h];
    ushort4 u0 = *(const ushort4*)(xpb + (size_t)s0 * HC + h * CCH + c4);
    ushort4 u1 = *(const ushort4*)(xpb + (size_t)s1 * HC + h * CCH + c4);
    z += w0 + w1;
    a0 += w0 * bf2f(u0.x) + w1 * bf2f(u1.x);
    a1 += w0 * bf2f(u0.y) + w1 * bf2f(u1.y);
    a2 += w0 * bf2f(u0.z) + w1 * bf2f(u1.z);
    a3 += w0 * bf2f(u0.w) + w1 * bf2f(u1.w);
  }
  if (j < end) {
    int s0 = ssrc2[j];
    float w0 = wqf[(size_t)j * NH + h];
    ushort4 u0 = *(const ushort4*)(xpb + (size_t)s0 * HC + h * CCH + c4);
    z += w0;
    a0 += w0 * bf2f(u0.x);
    a1 += w0 * bf2f(u0.y);
    a2 += w0 * bf2f(u0.z);
    a3 += w0 * bf2f(u0.w);
  }
  float inv = 0.25f / (z + 1e-16f);
  a0 *= inv; a1 *= inv; a2 *= inv; a3 *= inv;
  a0 += __shfl_down(a0, 32); a1 += __shfl_down(a1, 32);
  a2 += __shfl_down(a2, 32); a3 += __shfl_down(a3, 32);
  a0 += __shfl_down(a0, 16); a1 += __shfl_down(a1, 16);
  a2 += __shfl_down(a2, 16); a3 += __shfl_down(a3, 16);
  if (lane < 16) {
    const float4 b4 = *(const float4*)(bias + lane * 4);
    float4 o;
    o.x = a0 + b4.x; o.y = a1 + b4.y; o.z = a2 + b4.z; o.w = a3 + b4.w;
    *(float4*)(out + (size_t)d * CCH + lane * 4) = o;
  }
}

extern "C" void kernel_launch(void* const* d_in, const int* in_sizes, int n_in,
                              void* d_out, int out_size, void* d_ws, size_t ws_size,
                              hipStream_t stream) {
  const float* x        = (const float*)d_in[0];
  const int*   eidx     = (const int*)d_in[1];
  const int*   etype    = (const int*)d_in[2];
  const float* rel_emb  = (const float*)d_in[3];
  const float* W        = (const float*)d_in[4];
  const float* att_src  = (const float*)d_in[5];
  const float* att_dst  = (const float*)d_in[6];
  const float* W_edge   = (const float*)d_in[7];
  const float* att_edge = (const float*)d_in[8];
  const float* bias     = (const float*)d_in[9];
  float* out = (float*)d_out;

  const int Nn = in_sizes[0] / IN_DIM;
  const int E  = in_sizes[1] / 2;
  const int R  = in_sizes[3] / IN_DIM;
  const int* src = eidx;
  const int* dst = eidx + E;

  char* ws = (char*)d_ws;
  size_t off = 0;
  auto alloc = [&](size_t bytes) {
    void* p = ws + off;
    off = (off + bytes + 255) & ~(size_t)255;
    return p;
  };
  unsigned short* xpb = (unsigned short*)alloc((size_t)Nn * HC * 2);
  float* a_srcv = (float*)alloc((size_t)Nn * NH * 4);
  float* a_dstv = (float*)alloc((size_t)Nn * NH * 4);
  float* a_rel  = (float*)alloc((size_t)R * NH * 4);
  int*   counts = (int*)alloc((size_t)Nn * 4);
  int*   offsets= (int*)alloc((size_t)(Nn + 1) * 4);
  int*   cursor = (int*)alloc((size_t)Nn * 4);
  int*   bsum   = (int*)alloc(256 * 4);
  int*   bbase  = (int*)alloc(256 * 4);
  int*   ssrc2  = (int*)alloc((size_t)E * 4);
  float* wq     = (float*)alloc((size_t)E * NH * 4);

  const int NB = (Nn + 4095) / 4096;  // <= 64 required (Nn <= 262144)

  hipMemsetAsync(counts, 0, (size_t)Nn * 4, stream);

  hipLaunchKernelGGL(rel_attn_k, dim3(R), dim3(64), 0, stream,
                     rel_emb, W_edge, att_edge, a_rel);
  hipLaunchKernelGGL(gemm_mfma_k, dim3(4, (Nn + 127) / 128), dim3(256), 0, stream,
                     x, W, att_src, att_dst, xpb, a_srcv, a_dstv, Nn);
  hipLaunchKernelGGL(hist_k, dim3((E + 255) / 256), dim3(256), 0, stream, dst, counts, E);
  hipLaunchKernelGGL(scanA_k, dim3(NB), dim3(256), 0, stream, counts, bsum, Nn);
  hipLaunchKernelGGL(scanB_k, dim3(1), dim3(64), 0, stream, bsum, bbase, NB, offsets, Nn, E);
  hipLaunchKernelGGL(scanC_k, dim3(NB), dim3(256), 0, stream, counts, bbase, offsets, cursor, Nn);
  hipLaunchKernelGGL(edge_w_k, dim3((E + 255) / 256), dim3(256), 0, stream,
                     src, dst, etype, a_srcv, a_dstv, a_rel, R, cursor, ssrc2, wq, E);
  hipLaunchKernelGGL(gat_out_k, dim3((Nn + 3) / 4), dim3(256), 0, stream,
                     offsets, ssrc2, wq, xpb, bias, out, Nn);
}